// Round 1
// baseline (610.110 us; speedup 1.0000x reference)
//
#include <hip/hip_runtime.h>
#include <hip/hip_bf16.h>

typedef __attribute__((ext_vector_type(4))) float f32x4;
typedef __attribute__((ext_vector_type(8))) short bf16x8;
typedef __attribute__((ext_vector_type(4))) short bf16x4;

#define DEVI static __device__ __forceinline__

constexpr int Bn = 4, Sn = 2048, Hn = 1024, NHn = 16, HDn = 64;
constexpr int Kn = 1024, Nn = 1024;               // GEMM K and N (all 4 GEMMs)
constexpr float QSCALE = 0.18033688011112042f;    // log2(e)/8 : folds 1/sqrt(64) and exp->exp2

DEVI unsigned short f2bf(float x) {               // RNE f32->bf16
    union { float f; unsigned u; } v; v.f = x;
    unsigned r = v.u + 0x7fffu + ((v.u >> 16) & 1u);
    return (unsigned short)(r >> 16);
}

DEVI f32x4 mfma16(bf16x8 a, bf16x8 b, f32x4 c) {
    return __builtin_amdgcn_mfma_f32_16x16x32_bf16(a, b, c, 0, 0, 0);
}

typedef const __attribute__((address_space(1))) void* gas1_t;
typedef __attribute__((address_space(3))) void* gas3_t;

// ---------------- weight fp32 -> bf16 ----------------
__global__ void convert_w_kernel(const float* __restrict__ w0, const float* __restrict__ w1,
                                 const float* __restrict__ w2, const float* __restrict__ w3,
                                 unsigned short* __restrict__ out)
{
    int mat = blockIdx.x >> 10;                              // 1024 blocks per 1M-elem matrix
    int i4  = ((blockIdx.x & 1023) << 8) + threadIdx.x;      // float4 index within matrix
    const float* w = mat == 0 ? w0 : mat == 1 ? w1 : mat == 2 ? w2 : w3;
    f32x4 v = *reinterpret_cast<const f32x4*>(w + (size_t)i4 * 4);
    union { unsigned short u[4]; bf16x4 s; } pk;
    pk.u[0] = f2bf(v[0]); pk.u[1] = f2bf(v[1]); pk.u[2] = f2bf(v[2]); pk.u[3] = f2bf(v[3]);
    *reinterpret_cast<bf16x4*>(out + (((size_t)mat) << 20) + (size_t)i4 * 4) = pk.s;
}

// ---------------- shared 128x128x(K=1024) GEMM body ----------------
// C[M rows][1024] = A[M][1024] @ W[1024 rows][1024]^T + bias   (W row-major = B^T layout)
// out_mode 0: bf16 out[((b*NH+h)*S+s)*64+d] * scale   (Q / K layouts)
// out_mode 1: bf16 out[((b*NH+h)*64+d)*S+s]           (V transposed)
// out_mode 2: fp32 out[row*1024+col]                  (final output)
template<bool A_BF16>
DEVI void gemm_body(const void* __restrict__ Av, const unsigned short* __restrict__ Bw,
                    const float* __restrict__ bias, void* __restrict__ Out,
                    float scale, int out_mode)
{
    __shared__ __align__(16) unsigned short As[128 * 32];
    __shared__ __align__(16) unsigned short Bs[128 * 32];

    const int tid = threadIdx.x;
    const int wid = tid >> 6, lane = tid & 63;
    const int lhi = lane >> 4, llo = lane & 15;
    const int bx = blockIdx.x & 7;          // 8 col-blocks
    const int by = blockIdx.x >> 3;         // 64 row-blocks
    const int brow = by * 128, bcol = bx * 128;
    const int wr = wid >> 1, wc = wid & 1;  // 2x2 wave grid, 64x64 per wave

    f32x4 acc[4][4] = {};

    for (int kt = 0; kt < Kn / 32; ++kt) {
        __syncthreads();
        // --- B tile: 128 rows x 32 cols bf16 via global_load_lds (2 rounds x 256 lanes x 16B)
        #pragma unroll
        for (int r = 0; r < 2; ++r) {
            int lin = r * 256 + tid;
            int row = lin >> 2, kc = (lin & 3) * 8;
            const unsigned short* g = Bw + (size_t)(bcol + row) * Kn + kt * 32 + kc;
            unsigned short* ldst = Bs + (size_t)(r * 256 + wid * 64) * 8;   // wave-uniform base
            __builtin_amdgcn_global_load_lds((gas1_t)g, (gas3_t)ldst, 16, 0, 0);
        }
        // --- A tile
        if constexpr (A_BF16) {
            const unsigned short* A = (const unsigned short*)Av;
            #pragma unroll
            for (int r = 0; r < 2; ++r) {
                int lin = r * 256 + tid;
                int row = lin >> 2, kc = (lin & 3) * 8;
                const unsigned short* g = A + (size_t)(brow + row) * Kn + kt * 32 + kc;
                unsigned short* ldst = As + (size_t)(r * 256 + wid * 64) * 8;
                __builtin_amdgcn_global_load_lds((gas1_t)g, (gas3_t)ldst, 16, 0, 0);
            }
        } else {
            const float* A = (const float*)Av;
            #pragma unroll
            for (int r = 0; r < 4; ++r) {          // 4 rounds x 256 lanes x float4
                int lin = r * 256 + tid;
                int row = lin >> 3, kc = (lin & 7) * 4;
                f32x4 v = *reinterpret_cast<const f32x4*>(A + (size_t)(brow + row) * Kn + kt * 32 + kc);
                union { unsigned short u[4]; bf16x4 s; } pk;
                pk.u[0] = f2bf(v[0]); pk.u[1] = f2bf(v[1]);
                pk.u[2] = f2bf(v[2]); pk.u[3] = f2bf(v[3]);
                *reinterpret_cast<bf16x4*>(As + row * 32 + kc) = pk.s;
            }
        }
        __syncthreads();

        // --- compute: 16 MFMA, 8 ds_read_b128
        bf16x8 a[4], b[4];
        #pragma unroll
        for (int m = 0; m < 4; ++m)
            a[m] = *reinterpret_cast<const bf16x8*>(As + (wr * 64 + m * 16 + llo) * 32 + lhi * 8);
        #pragma unroll
        for (int n = 0; n < 4; ++n)
            b[n] = *reinterpret_cast<const bf16x8*>(Bs + (wc * 64 + n * 16 + llo) * 32 + lhi * 8);
        #pragma unroll
        for (int m = 0; m < 4; ++m)
            #pragma unroll
            for (int n = 0; n < 4; ++n)
                acc[m][n] = mfma16(a[m], b[n], acc[m][n]);
    }

    // --- epilogue.  C/D layout: col = lane&15, row = (lane>>4)*4 + reg  [m89-verified]
    #pragma unroll
    for (int m = 0; m < 4; ++m) {
        #pragma unroll
        for (int n = 0; n < 4; ++n) {
            const int col  = bcol + wc * 64 + n * 16 + llo;
            const int row0 = brow + wr * 64 + m * 16 + lhi * 4;
            const float bv = bias[col];
            if (out_mode == 0) {
                unsigned short* O = (unsigned short*)Out;
                const int h = col >> 6, d = col & 63;
                #pragma unroll
                for (int r = 0; r < 4; ++r) {
                    int rowm = row0 + r;
                    int bb = rowm >> 11, ss = rowm & 2047;
                    O[((((size_t)bb * NHn + h) * Sn + ss) << 6) + d] =
                        f2bf((acc[m][n][r] + bv) * scale);
                }
            } else if (out_mode == 1) {
                unsigned short* O = (unsigned short*)Out;
                const int h = col >> 6, d = col & 63;
                const int bb = row0 >> 11, ss = row0 & 2047;   // 4 consecutive s, same b
                union { unsigned short u[4]; bf16x4 s; } pk;
                #pragma unroll
                for (int r = 0; r < 4; ++r) pk.u[r] = f2bf(acc[m][n][r] + bv);
                *reinterpret_cast<bf16x4*>(O + (((size_t)bb * NHn + h) * HDn + d) * Sn + ss) = pk.s;
            } else {
                float* O = (float*)Out;
                #pragma unroll
                for (int r = 0; r < 4; ++r)
                    O[(size_t)(row0 + r) * Nn + col] = acc[m][n][r] + bv;
            }
        }
    }
}

// fused QKV projection: blockIdx.z selects {Q,K,V} -> 1536 blocks total (6/CU)
__global__ __launch_bounds__(256, 2)
void qkv_proj_kernel(const float* __restrict__ xq, const float* __restrict__ xk,
                     const float* __restrict__ xv, const unsigned short* __restrict__ Wb,
                     const float* __restrict__ bq, const float* __restrict__ bk,
                     const float* __restrict__ bv,
                     unsigned short* __restrict__ Qw, unsigned short* __restrict__ Kw,
                     unsigned short* __restrict__ Vw)
{
    const int z = blockIdx.z;
    const float* A           = z == 0 ? xq : z == 1 ? xk : xv;
    const unsigned short* W  = Wb + (((size_t)z) << 20);
    const float* bias        = z == 0 ? bq : z == 1 ? bk : bv;
    unsigned short* Out      = z == 0 ? Qw : z == 1 ? Kw : Vw;
    const float scale        = z == 0 ? QSCALE : 1.0f;
    const int mode           = z == 2 ? 1 : 0;
    gemm_body<false>(A, W, bias, Out, scale, mode);
}

__global__ __launch_bounds__(256, 2)
void out_proj_kernel(const unsigned short* __restrict__ attn, const unsigned short* __restrict__ Wo,
                     const float* __restrict__ bo, float* __restrict__ out)
{
    gemm_body<true>(attn, Wo, bo, out, 1.0f, 2);
}

// ---------------- flash attention ----------------
// Q: [B,NH,S,64] bf16, pre-scaled by log2(e)/8.  K: [B,NH,S,64] bf16.  Vt: [B,NH,64,S] bf16.
// 4 waves/block, wave owns 16 Q rows; 64-key tiles; online softmax in exp2 domain.
__global__ __launch_bounds__(256, 2)
void attn_kernel(const unsigned short* __restrict__ Q, const unsigned short* __restrict__ K,
                 const unsigned short* __restrict__ Vt, unsigned short* __restrict__ On)
{
    __shared__ __align__(16) unsigned short P_lds[4][16 * 72];   // per-wave, +8 pad breaks conflicts

    const int tid = threadIdx.x;
    const int wid = tid >> 6, lane = tid & 63;
    const int lhi = lane >> 4, llo = lane & 15;
    const int bh = blockIdx.x >> 5;          // b*16+h
    const int qt = blockIdx.x & 31;          // 64-row Q tile
    const int q0 = qt * 64 + wid * 16;

    const unsigned short* Qb = Q + (size_t)bh * Sn * HDn;
    const unsigned short* Kb = K + (size_t)bh * Sn * HDn;
    const unsigned short* Vb = Vt + (size_t)bh * HDn * Sn;

    bf16x8 aq[2];
    #pragma unroll
    for (int kk = 0; kk < 2; ++kk)
        aq[kk] = *reinterpret_cast<const bf16x8*>(Qb + (size_t)(q0 + llo) * HDn + kk * 32 + lhi * 8);

    f32x4 o[4] = {};
    float m_run[4], l_run[4];
    #pragma unroll
    for (int r = 0; r < 4; ++r) { m_run[r] = -1e30f; l_run[r] = 0.f; }

    unsigned short* Pw = P_lds[wid];

    for (int kt = 0; kt < Sn / 64; ++kt) {
        const int key0 = kt * 64;
        // --- S = Q'K^T (already in log2 domain)
        f32x4 sc[4] = {};
        #pragma unroll
        for (int kc = 0; kc < 4; ++kc) {
            bf16x8 bk0 = *reinterpret_cast<const bf16x8*>(Kb + (size_t)(key0 + kc * 16 + llo) * HDn + lhi * 8);
            bf16x8 bk1 = *reinterpret_cast<const bf16x8*>(Kb + (size_t)(key0 + kc * 16 + llo) * HDn + 32 + lhi * 8);
            sc[kc] = mfma16(aq[0], bk0, sc[kc]);
            sc[kc] = mfma16(aq[1], bk1, sc[kc]);
        }
        // --- online softmax (rows live in 16-lane groups; reg r = row (lane>>4)*4+r)
        float tmax[4];
        #pragma unroll
        for (int r = 0; r < 4; ++r)
            tmax[r] = fmaxf(fmaxf(sc[0][r], sc[1][r]), fmaxf(sc[2][r], sc[3][r]));
        #pragma unroll
        for (int off = 1; off < 16; off <<= 1)
            #pragma unroll
            for (int r = 0; r < 4; ++r)
                tmax[r] = fmaxf(tmax[r], __shfl_xor(tmax[r], off, 64));
        float corr[4], rsum[4];
        #pragma unroll
        for (int r = 0; r < 4; ++r) {
            float mn = fmaxf(m_run[r], tmax[r]);
            corr[r] = exp2f(m_run[r] - mn);
            m_run[r] = mn;
            rsum[r] = 0.f;
        }
        #pragma unroll
        for (int kc = 0; kc < 4; ++kc)
            #pragma unroll
            for (int r = 0; r < 4; ++r) {
                float p = exp2f(sc[kc][r] - m_run[r]);
                sc[kc][r] = p;
                rsum[r] += p;
            }
        #pragma unroll
        for (int off = 1; off < 16; off <<= 1)
            #pragma unroll
            for (int r = 0; r < 4; ++r)
                rsum[r] += __shfl_xor(rsum[r], off, 64);
        #pragma unroll
        for (int r = 0; r < 4; ++r)
            l_run[r] = l_run[r] * corr[r] + rsum[r];
        #pragma unroll
        for (int f = 0; f < 4; ++f)
            #pragma unroll
            for (int r = 0; r < 4; ++r)
                o[f][r] *= corr[r];
        // --- P (C-layout) -> LDS -> A-frag layout
        #pragma unroll
        for (int kc = 0; kc < 4; ++kc)
            #pragma unroll
            for (int r = 0; r < 4; ++r)
                Pw[(lhi * 4 + r) * 72 + kc * 16 + llo] = f2bf(sc[kc][r]);
        asm volatile("s_waitcnt lgkmcnt(0)" ::: "memory");
        __builtin_amdgcn_sched_barrier(0);
        bf16x8 ap0 = *reinterpret_cast<const bf16x8*>(Pw + llo * 72 + lhi * 8);
        bf16x8 ap1 = *reinterpret_cast<const bf16x8*>(Pw + llo * 72 + 32 + lhi * 8);
        // --- O += P @ V  (V pre-transposed: contiguous 16B b-frag loads)
        #pragma unroll
        for (int f = 0; f < 4; ++f) {
            bf16x8 bv0 = *reinterpret_cast<const bf16x8*>(Vb + (size_t)(f * 16 + llo) * Sn + key0 + lhi * 8);
            bf16x8 bv1 = *reinterpret_cast<const bf16x8*>(Vb + (size_t)(f * 16 + llo) * Sn + key0 + 32 + lhi * 8);
            o[f] = mfma16(ap0, bv0, o[f]);
            o[f] = mfma16(ap1, bv1, o[f]);
        }
        asm volatile("s_waitcnt lgkmcnt(0)" ::: "memory");
        __builtin_amdgcn_sched_barrier(0);
    }

    const int b = bh >> 4, h = bh & 15;
    float inv[4];
    #pragma unroll
    for (int r = 0; r < 4; ++r) inv[r] = 1.f / l_run[r];
    #pragma unroll
    for (int f = 0; f < 4; ++f)
        #pragma unroll
        for (int r = 0; r < 4; ++r) {
            int qrow = q0 + lhi * 4 + r;
            On[((size_t)b * Sn + qrow) * Hn + h * 64 + f * 16 + llo] = f2bf(o[f][r] * inv[r]);
        }
}

// ---------------- launch ----------------
extern "C" void kernel_launch(void* const* d_in, const int* in_sizes, int n_in,
                              void* d_out, int out_size, void* d_ws, size_t ws_size,
                              hipStream_t stream)
{
    (void)in_sizes; (void)n_in; (void)out_size;
    const float* q  = (const float*)d_in[0];
    const float* k  = (const float*)d_in[1];
    const float* v  = (const float*)d_in[2];
    const float* Wq = (const float*)d_in[3];
    const float* bq = (const float*)d_in[4];
    const float* Wk = (const float*)d_in[5];
    const float* bk = (const float*)d_in[6];
    const float* Wv = (const float*)d_in[7];
    const float* bv = (const float*)d_in[8];
    const float* Wo = (const float*)d_in[9];
    const float* bo = (const float*)d_in[10];
    float* out = (float*)d_out;

    if (ws_size < (size_t)72 * 1024 * 1024) return;   // need 72 MB scratch

    unsigned short* Wb = (unsigned short*)d_ws;                    // 4M elems (4 weights bf16)
    unsigned short* Qw = Wb + (size_t)4 * 1024 * 1024;             // [B,NH,S,64] bf16, pre-scaled
    unsigned short* Kw = Qw + (size_t)8 * 1024 * 1024;             // [B,NH,S,64] bf16
    unsigned short* Vw = Kw + (size_t)8 * 1024 * 1024;             // [B,NH,64,S] bf16 (transposed)
    unsigned short* Aw = Vw + (size_t)8 * 1024 * 1024;             // attn out [B,S,H] bf16

    convert_w_kernel<<<4096, 256, 0, stream>>>(Wq, Wk, Wv, Wo, Wb);
    qkv_proj_kernel<<<dim3(512, 1, 3), 256, 0, stream>>>(q, k, v, Wb, bq, bk, bv, Qw, Kw, Vw);
    attn_kernel<<<2048, 256, 0, stream>>>(Qw, Kw, Vw, Aw);
    out_proj_kernel<<<512, 256, 0, stream>>>(Aw, Wb + ((size_t)3 << 20), bo, out);
}

// Round 2
// 442.431 us; speedup vs baseline: 1.3790x; 1.3790x over previous
//
#include <hip/hip_runtime.h>
#include <hip/hip_bf16.h>

typedef __attribute__((ext_vector_type(4)))  float f32x4;
typedef __attribute__((ext_vector_type(16))) float f32x16;
typedef __attribute__((ext_vector_type(8)))  short bf16x8;
typedef __attribute__((ext_vector_type(4)))  short bf16x4;

#define DEVI static __device__ __forceinline__

constexpr int Bn = 4, Sn = 2048, Hn = 1024, NHn = 16, HDn = 64;
constexpr int Kn = 1024, Nn = 1024;               // GEMM K and N (all 4 GEMMs)
constexpr float QSCALE = 0.18033688011112042f;    // log2(e)/8 : folds 1/sqrt(64) and exp->exp2

DEVI unsigned short f2bf(float x) {               // RNE f32->bf16
    union { float f; unsigned u; } v; v.f = x;
    unsigned r = v.u + 0x7fffu + ((v.u >> 16) & 1u);
    return (unsigned short)(r >> 16);
}

DEVI f32x4 mfma16(bf16x8 a, bf16x8 b, f32x4 c) {
    return __builtin_amdgcn_mfma_f32_16x16x32_bf16(a, b, c, 0, 0, 0);
}
DEVI f32x16 mfma32(bf16x8 a, bf16x8 b, f32x16 c) {
    return __builtin_amdgcn_mfma_f32_32x32x16_bf16(a, b, c, 0, 0, 0);
}
DEVI unsigned cvt_pk_bf16(float lo, float hi) {   // low16 <- lo, high16 <- hi
    unsigned r;
    asm("v_cvt_pk_bf16_f32 %0, %1, %2" : "=v"(r) : "v"(lo), "v"(hi));
    return r;
}

typedef const __attribute__((address_space(1))) void* gas1_t;
typedef __attribute__((address_space(3))) void* gas3_t;

// ---------------- weight fp32 -> bf16 ----------------
__global__ void convert_w_kernel(const float* __restrict__ w0, const float* __restrict__ w1,
                                 const float* __restrict__ w2, const float* __restrict__ w3,
                                 unsigned short* __restrict__ out)
{
    int mat = blockIdx.x >> 10;
    int i4  = ((blockIdx.x & 1023) << 8) + threadIdx.x;
    const float* w = mat == 0 ? w0 : mat == 1 ? w1 : mat == 2 ? w2 : w3;
    f32x4 v = *reinterpret_cast<const f32x4*>(w + (size_t)i4 * 4);
    union { unsigned short u[4]; bf16x4 s; } pk;
    pk.u[0] = f2bf(v[0]); pk.u[1] = f2bf(v[1]); pk.u[2] = f2bf(v[2]); pk.u[3] = f2bf(v[3]);
    *reinterpret_cast<bf16x4*>(out + (((size_t)mat) << 20) + (size_t)i4 * 4) = pk.s;
}

// ---------------- shared 128x128x(K=1024) GEMM body ----------------
template<bool A_BF16>
DEVI void gemm_body(const void* __restrict__ Av, const unsigned short* __restrict__ Bw,
                    const float* __restrict__ bias, void* __restrict__ Out,
                    float scale, int out_mode)
{
    __shared__ __align__(16) unsigned short As[128 * 32];
    __shared__ __align__(16) unsigned short Bs[128 * 32];

    const int tid = threadIdx.x;
    const int wid = tid >> 6, lane = tid & 63;
    const int lhi = lane >> 4, llo = lane & 15;
    const int bx = blockIdx.x & 7;
    const int by = blockIdx.x >> 3;
    const int brow = by * 128, bcol = bx * 128;
    const int wr = wid >> 1, wc = wid & 1;

    f32x4 acc[4][4] = {};

    for (int kt = 0; kt < Kn / 32; ++kt) {
        __syncthreads();
        #pragma unroll
        for (int r = 0; r < 2; ++r) {
            int lin = r * 256 + tid;
            int row = lin >> 2, kc = (lin & 3) * 8;
            const unsigned short* g = Bw + (size_t)(bcol + row) * Kn + kt * 32 + kc;
            unsigned short* ldst = Bs + (size_t)(r * 256 + wid * 64) * 8;
            __builtin_amdgcn_global_load_lds((gas1_t)g, (gas3_t)ldst, 16, 0, 0);
        }
        if constexpr (A_BF16) {
            const unsigned short* A = (const unsigned short*)Av;
            #pragma unroll
            for (int r = 0; r < 2; ++r) {
                int lin = r * 256 + tid;
                int row = lin >> 2, kc = (lin & 3) * 8;
                const unsigned short* g = A + (size_t)(brow + row) * Kn + kt * 32 + kc;
                unsigned short* ldst = As + (size_t)(r * 256 + wid * 64) * 8;
                __builtin_amdgcn_global_load_lds((gas1_t)g, (gas3_t)ldst, 16, 0, 0);
            }
        } else {
            const float* A = (const float*)Av;
            #pragma unroll
            for (int r = 0; r < 4; ++r) {
                int lin = r * 256 + tid;
                int row = lin >> 3, kc = (lin & 7) * 4;
                f32x4 v = *reinterpret_cast<const f32x4*>(A + (size_t)(brow + row) * Kn + kt * 32 + kc);
                union { unsigned short u[4]; bf16x4 s; } pk;
                pk.u[0] = f2bf(v[0]); pk.u[1] = f2bf(v[1]);
                pk.u[2] = f2bf(v[2]); pk.u[3] = f2bf(v[3]);
                *reinterpret_cast<bf16x4*>(As + row * 32 + kc) = pk.s;
            }
        }
        __syncthreads();

        bf16x8 a[4], b[4];
        #pragma unroll
        for (int m = 0; m < 4; ++m)
            a[m] = *reinterpret_cast<const bf16x8*>(As + (wr * 64 + m * 16 + llo) * 32 + lhi * 8);
        #pragma unroll
        for (int n = 0; n < 4; ++n)
            b[n] = *reinterpret_cast<const bf16x8*>(Bs + (wc * 64 + n * 16 + llo) * 32 + lhi * 8);
        #pragma unroll
        for (int m = 0; m < 4; ++m)
            #pragma unroll
            for (int n = 0; n < 4; ++n)
                acc[m][n] = mfma16(a[m], b[n], acc[m][n]);
    }

    #pragma unroll
    for (int m = 0; m < 4; ++m) {
        #pragma unroll
        for (int n = 0; n < 4; ++n) {
            const int col  = bcol + wc * 64 + n * 16 + llo;
            const int row0 = brow + wr * 64 + m * 16 + lhi * 4;
            const float bv = bias[col];
            if (out_mode == 0) {
                unsigned short* O = (unsigned short*)Out;
                const int h = col >> 6, d = col & 63;
                #pragma unroll
                for (int r = 0; r < 4; ++r) {
                    int rowm = row0 + r;
                    int bb = rowm >> 11, ss = rowm & 2047;
                    O[((((size_t)bb * NHn + h) * Sn + ss) << 6) + d] =
                        f2bf((acc[m][n][r] + bv) * scale);
                }
            } else if (out_mode == 1) {
                unsigned short* O = (unsigned short*)Out;
                const int h = col >> 6, d = col & 63;
                const int bb = row0 >> 11, ss = row0 & 2047;
                union { unsigned short u[4]; bf16x4 s; } pk;
                #pragma unroll
                for (int r = 0; r < 4; ++r) pk.u[r] = f2bf(acc[m][n][r] + bv);
                *reinterpret_cast<bf16x4*>(O + (((size_t)bb * NHn + h) * HDn + d) * Sn + ss) = pk.s;
            } else {
                float* O = (float*)Out;
                #pragma unroll
                for (int r = 0; r < 4; ++r)
                    O[(size_t)(row0 + r) * Nn + col] = acc[m][n][r] + bv;
            }
        }
    }
}

__global__ __launch_bounds__(256, 2)
void qkv_proj_kernel(const float* __restrict__ xq, const float* __restrict__ xk,
                     const float* __restrict__ xv, const unsigned short* __restrict__ Wb,
                     const float* __restrict__ bq, const float* __restrict__ bk,
                     const float* __restrict__ bv,
                     unsigned short* __restrict__ Qw, unsigned short* __restrict__ Kw,
                     unsigned short* __restrict__ Vw)
{
    const int z = blockIdx.z;
    const float* A           = z == 0 ? xq : z == 1 ? xk : xv;
    const unsigned short* W  = Wb + (((size_t)z) << 20);
    const float* bias        = z == 0 ? bq : z == 1 ? bk : bv;
    unsigned short* Out      = z == 0 ? Qw : z == 1 ? Kw : Vw;
    const float scale        = z == 0 ? QSCALE : 1.0f;
    const int mode           = z == 2 ? 1 : 0;
    gemm_body<false>(A, W, bias, Out, scale, mode);
}

__global__ __launch_bounds__(256, 2)
void out_proj_kernel(const unsigned short* __restrict__ attn, const unsigned short* __restrict__ Wo,
                     const float* __restrict__ bo, float* __restrict__ out)
{
    gemm_body<true>(attn, Wo, bo, out, 1.0f, 2);
}

// ---------------- flash attention (32x32 MFMA, swapped QK^T, register softmax) ----------------
// Q: [B,NH,S,64] bf16 pre-scaled by log2(e)/8.  K: [B,NH,S,64].  Vt: [B,NH,64,S].
// 4 waves/block, wave owns 32 q rows (q = lane&31; lane>>5 = k-half).
// QK^T: sc = mfma(K, Q) -> P^T[key][q]; lane holds 32 P values of ONE q-row.
// softmax: lane-local tree + single shfl_xor(32) per reduce.
// PV: O^T[d][q] = mfma(Vt, P); P redistributed in-register (cvt_pk + shfl_xor(32)).
__global__ __launch_bounds__(256, 2)
void attn_kernel(const unsigned short* __restrict__ Q, const unsigned short* __restrict__ K,
                 const unsigned short* __restrict__ Vt, unsigned short* __restrict__ On)
{
    const int tid = threadIdx.x;
    const int wid = tid >> 6, lane = tid & 63;
    const int l31 = lane & 31, h = lane >> 5;
    const int bh = blockIdx.x >> 4;          // b*16 + head
    const int qt = blockIdx.x & 15;          // 128-row q tile
    const int q0 = qt * 128 + wid * 32;

    const unsigned short* Qb = Q + (size_t)bh * Sn * HDn;
    const unsigned short* Kb = K + (size_t)bh * Sn * HDn;
    const unsigned short* Vb = Vt + (size_t)bh * HDn * Sn;

    // Q fragment: b-operand rows = q, k = d.  4 k-steps of 16.
    bf16x8 qf[4];
    #pragma unroll
    for (int sd = 0; sd < 4; ++sd)
        qf[sd] = *reinterpret_cast<const bf16x8*>(Qb + (size_t)(q0 + l31) * HDn + sd * 16 + h * 8);

    f32x16 o0 = {}, o1 = {};                 // O^T accum: rows d = [0..32)+32*nb, col q = l31
    float m_run = -1e30f, l_run = 0.f;

    for (int kt = 0; kt < Sn / 64; ++kt) {
        const int key0 = kt * 64;

        // --- QK^T swapped: sc[kc] = P^T for keys [key0+32kc, +32)
        f32x16 sc0 = {}, sc1 = {};
        #pragma unroll
        for (int sd = 0; sd < 4; ++sd) {
            bf16x8 ka = *reinterpret_cast<const bf16x8*>(Kb + (size_t)(key0 + l31) * HDn + sd * 16 + h * 8);
            sc0 = mfma32(ka, qf[sd], sc0);
        }
        #pragma unroll
        for (int sd = 0; sd < 4; ++sd) {
            bf16x8 ka = *reinterpret_cast<const bf16x8*>(Kb + (size_t)(key0 + 32 + l31) * HDn + sd * 16 + h * 8);
            sc1 = mfma32(ka, qf[sd], sc1);
        }

        // --- V prefetch (L2 latency hides under softmax).  a-operand rows = d, k = keys.
        bf16x8 va0[4], va1[4];               // [S = 16-key step]
        #pragma unroll
        for (int S = 0; S < 4; ++S) {
            va0[S] = *reinterpret_cast<const bf16x8*>(Vb + (size_t)l31 * Sn        + key0 + S * 16 + h * 8);
            va1[S] = *reinterpret_cast<const bf16x8*>(Vb + (size_t)(32 + l31) * Sn + key0 + S * 16 + h * 8);
        }

        // --- online softmax, lane-local (lane owns q = l31; halves merged via xor-32)
        float t[16];
        #pragma unroll
        for (int r = 0; r < 16; ++r) t[r] = fmaxf(sc0[r], sc1[r]);
        #pragma unroll
        for (int st = 8; st > 0; st >>= 1)
            #pragma unroll
            for (int r = 0; r < 8; ++r)
                if (r < st) t[r] = fmaxf(t[r], t[r + st]);
        float mx = fmaxf(t[0], __shfl_xor(t[0], 32, 64));
        float mnew = fmaxf(m_run, mx);
        float corr = exp2f(m_run - mnew);
        m_run = mnew;
        #pragma unroll
        for (int r = 0; r < 16; ++r) {
            sc0[r] = exp2f(sc0[r] - mnew);
            sc1[r] = exp2f(sc1[r] - mnew);
        }
        float s[16];
        #pragma unroll
        for (int r = 0; r < 16; ++r) s[r] = sc0[r] + sc1[r];
        #pragma unroll
        for (int st = 8; st > 0; st >>= 1)
            #pragma unroll
            for (int r = 0; r < 8; ++r)
                if (r < st) s[r] += s[r + st];
        float rs = s[0] + __shfl_xor(s[0], 32, 64);
        l_run = l_run * corr + rs;
        #pragma unroll
        for (int r = 0; r < 16; ++r) { o0[r] *= corr; o1[r] *= corr; }

        // --- pack P -> bf16 words.  Wp[kc][R][w]: regs 4R..4R+3 of kc-block as 2 u32.
        unsigned Wp[2][4][2];
        #pragma unroll
        for (int R = 0; R < 4; ++R) {
            Wp[0][R][0] = cvt_pk_bf16(sc0[4 * R],     sc0[4 * R + 1]);
            Wp[0][R][1] = cvt_pk_bf16(sc0[4 * R + 2], sc0[4 * R + 3]);
            Wp[1][R][0] = cvt_pk_bf16(sc1[4 * R],     sc1[4 * R + 1]);
            Wp[1][R][1] = cvt_pk_bf16(sc1[4 * R + 2], sc1[4 * R + 3]);
        }

        // --- PV: O^T += mfma(Vt, P).  b-frag rows = q; per 16-key step S = 2*kc + sp,
        // lane needs keys 16*sp*? -> j2=0,1 from h'=0's Wp[2sp+h], j2=2,3 from h'=1's.
        #pragma unroll
        for (int kc = 0; kc < 2; ++kc) {
            #pragma unroll
            for (int sp = 0; sp < 2; ++sp) {
                const int S = kc * 2 + sp;
                unsigned own0 = h ? Wp[kc][2 * sp + 1][0] : Wp[kc][2 * sp][0];
                unsigned own1 = h ? Wp[kc][2 * sp + 1][1] : Wp[kc][2 * sp][1];
                unsigned e0   = h ? Wp[kc][2 * sp][0]     : Wp[kc][2 * sp + 1][0];
                unsigned e1   = h ? Wp[kc][2 * sp][1]     : Wp[kc][2 * sp + 1][1];
                unsigned x0 = __shfl_xor(e0, 32, 64);    // partner's Wp[kc][2sp+h][0]
                unsigned x1 = __shfl_xor(e1, 32, 64);
                union { unsigned u[4]; bf16x8 v; } pb;
                pb.u[0] = h ? x0 : own0;
                pb.u[1] = h ? x1 : own1;
                pb.u[2] = h ? own0 : x0;
                pb.u[3] = h ? own1 : x1;
                o0 = mfma32(va0[S], pb.v, o0);
                o1 = mfma32(va1[S], pb.v, o1);
            }
        }
    }

    // --- epilogue: O^T rows d = (r&3)+8*(r>>2)+4h+32nb, col q = l31
    const float inv = 1.f / l_run;
    const int b = bh >> 4, hh = bh & 15;
    const int qg = q0 + l31;
    unsigned short* Orow = On + ((size_t)b * Sn + qg) * Hn + hh * 64;
    #pragma unroll
    for (int g = 0; g < 4; ++g) {
        union { unsigned short u[4]; bf16x4 s; } p0, p1;
        #pragma unroll
        for (int r = 0; r < 4; ++r) {
            p0.u[r] = f2bf(o0[4 * g + r] * inv);
            p1.u[r] = f2bf(o1[4 * g + r] * inv);
        }
        *reinterpret_cast<bf16x4*>(Orow + g * 8 + 4 * h)      = p0.s;
        *reinterpret_cast<bf16x4*>(Orow + 32 + g * 8 + 4 * h) = p1.s;
    }
}

// ---------------- launch ----------------
extern "C" void kernel_launch(void* const* d_in, const int* in_sizes, int n_in,
                              void* d_out, int out_size, void* d_ws, size_t ws_size,
                              hipStream_t stream)
{
    (void)in_sizes; (void)n_in; (void)out_size;
    const float* q  = (const float*)d_in[0];
    const float* k  = (const float*)d_in[1];
    const float* v  = (const float*)d_in[2];
    const float* Wq = (const float*)d_in[3];
    const float* bq = (const float*)d_in[4];
    const float* Wk = (const float*)d_in[5];
    const float* bk = (const float*)d_in[6];
    const float* Wv = (const float*)d_in[7];
    const float* bv = (const float*)d_in[8];
    const float* Wo = (const float*)d_in[9];
    const float* bo = (const float*)d_in[10];
    float* out = (float*)d_out;

    if (ws_size < (size_t)72 * 1024 * 1024) return;

    unsigned short* Wb = (unsigned short*)d_ws;
    unsigned short* Qw = Wb + (size_t)4 * 1024 * 1024;
    unsigned short* Kw = Qw + (size_t)8 * 1024 * 1024;
    unsigned short* Vw = Kw + (size_t)8 * 1024 * 1024;
    unsigned short* Aw = Vw + (size_t)8 * 1024 * 1024;

    convert_w_kernel<<<4096, 256, 0, stream>>>(Wq, Wk, Wv, Wo, Wb);
    qkv_proj_kernel<<<dim3(512, 1, 3), 256, 0, stream>>>(q, k, v, Wb, bq, bk, bv, Qw, Kw, Vw);
    attn_kernel<<<1024, 256, 0, stream>>>(Qw, Kw, Vw, Aw);
    out_proj_kernel<<<512, 256, 0, stream>>>(Aw, Wb + ((size_t)3 << 20), bo, out);
}

// Round 3
// 242.324 us; speedup vs baseline: 2.5177x; 1.8258x over previous
//
#include <hip/hip_runtime.h>
#include <hip/hip_bf16.h>

typedef __attribute__((ext_vector_type(4)))  float f32x4;
typedef __attribute__((ext_vector_type(16))) float f32x16;
typedef __attribute__((ext_vector_type(8)))  short bf16x8;
typedef __attribute__((ext_vector_type(4)))  short bf16x4;

#define DEVI static __device__ __forceinline__

constexpr int Bn = 4, Sn = 2048, Hn = 1024, NHn = 16, HDn = 64;
constexpr int Kn = 1024, Nn = 1024;               // GEMM K and N (all 4 GEMMs)
constexpr float QSCALE = 0.18033688011112042f;    // log2(e)/8 : folds 1/sqrt(64) and exp->exp2

DEVI unsigned short f2bf(float x) {               // RNE f32->bf16
    union { float f; unsigned u; } v; v.f = x;
    unsigned r = v.u + 0x7fffu + ((v.u >> 16) & 1u);
    return (unsigned short)(r >> 16);
}

DEVI f32x4 mfma16(bf16x8 a, bf16x8 b, f32x4 c) {
    return __builtin_amdgcn_mfma_f32_16x16x32_bf16(a, b, c, 0, 0, 0);
}
DEVI f32x16 mfma32(bf16x8 a, bf16x8 b, f32x16 c) {
    return __builtin_amdgcn_mfma_f32_32x32x16_bf16(a, b, c, 0, 0, 0);
}
DEVI unsigned cvt_pk_bf16(float lo, float hi) {
    unsigned r;
    asm("v_cvt_pk_bf16_f32 %0, %1, %2" : "=v"(r) : "v"(lo), "v"(hi));
    return r;
}

typedef const __attribute__((address_space(1))) void* gas1_t;
typedef __attribute__((address_space(3))) void* gas3_t;

// ---------------- weight fp32 -> bf16 ----------------
__global__ void convert_w_kernel(const float* __restrict__ w0, const float* __restrict__ w1,
                                 const float* __restrict__ w2, const float* __restrict__ w3,
                                 unsigned short* __restrict__ out)
{
    int mat = blockIdx.x >> 10;
    int i4  = ((blockIdx.x & 1023) << 8) + threadIdx.x;
    const float* w = mat == 0 ? w0 : mat == 1 ? w1 : mat == 2 ? w2 : w3;
    f32x4 v = *reinterpret_cast<const f32x4*>(w + (size_t)i4 * 4);
    union { unsigned short u[4]; bf16x4 s; } pk;
    pk.u[0] = f2bf(v[0]); pk.u[1] = f2bf(v[1]); pk.u[2] = f2bf(v[2]); pk.u[3] = f2bf(v[3]);
    *reinterpret_cast<bf16x4*>(out + (((size_t)mat) << 20) + (size_t)i4 * 4) = pk.s;
}

// ---------------- shared 128x128x(K=1024) GEMM body ----------------
template<bool A_BF16>
DEVI void gemm_body(const void* __restrict__ Av, const unsigned short* __restrict__ Bw,
                    const float* __restrict__ bias, void* __restrict__ Out,
                    float scale, int out_mode)
{
    __shared__ __align__(16) unsigned short As[128 * 32];
    __shared__ __align__(16) unsigned short Bs[128 * 32];

    const int tid = threadIdx.x;
    const int wid = tid >> 6, lane = tid & 63;
    const int lhi = lane >> 4, llo = lane & 15;
    // XCD-aware bijective swizzle, nwg=512 (T1): XCD x gets contiguous row-panels
    const int bid = blockIdx.x;
    const int sid = (bid & 7) * 64 + (bid >> 3);
    const int bx = sid & 7;
    const int by = sid >> 3;
    const int brow = by * 128, bcol = bx * 128;
    const int wr = wid >> 1, wc = wid & 1;

    f32x4 acc[4][4] = {};

    for (int kt = 0; kt < Kn / 32; ++kt) {
        __syncthreads();
        #pragma unroll
        for (int r = 0; r < 2; ++r) {
            int lin = r * 256 + tid;
            int row = lin >> 2, kc = (lin & 3) * 8;
            const unsigned short* g = Bw + (size_t)(bcol + row) * Kn + kt * 32 + kc;
            unsigned short* ldst = Bs + (size_t)(r * 256 + wid * 64) * 8;
            __builtin_amdgcn_global_load_lds((gas1_t)g, (gas3_t)ldst, 16, 0, 0);
        }
        if constexpr (A_BF16) {
            const unsigned short* A = (const unsigned short*)Av;
            #pragma unroll
            for (int r = 0; r < 2; ++r) {
                int lin = r * 256 + tid;
                int row = lin >> 2, kc = (lin & 3) * 8;
                const unsigned short* g = A + (size_t)(brow + row) * Kn + kt * 32 + kc;
                unsigned short* ldst = As + (size_t)(r * 256 + wid * 64) * 8;
                __builtin_amdgcn_global_load_lds((gas1_t)g, (gas3_t)ldst, 16, 0, 0);
            }
        } else {
            const float* A = (const float*)Av;
            #pragma unroll
            for (int r = 0; r < 4; ++r) {
                int lin = r * 256 + tid;
                int row = lin >> 3, kc = (lin & 7) * 4;
                f32x4 v = *reinterpret_cast<const f32x4*>(A + (size_t)(brow + row) * Kn + kt * 32 + kc);
                union { unsigned short u[4]; bf16x4 s; } pk;
                pk.u[0] = f2bf(v[0]); pk.u[1] = f2bf(v[1]);
                pk.u[2] = f2bf(v[2]); pk.u[3] = f2bf(v[3]);
                *reinterpret_cast<bf16x4*>(As + row * 32 + kc) = pk.s;
            }
        }
        __syncthreads();

        bf16x8 a[4], b[4];
        #pragma unroll
        for (int m = 0; m < 4; ++m)
            a[m] = *reinterpret_cast<const bf16x8*>(As + (wr * 64 + m * 16 + llo) * 32 + lhi * 8);
        #pragma unroll
        for (int n = 0; n < 4; ++n)
            b[n] = *reinterpret_cast<const bf16x8*>(Bs + (wc * 64 + n * 16 + llo) * 32 + lhi * 8);
        #pragma unroll
        for (int m = 0; m < 4; ++m)
            #pragma unroll
            for (int n = 0; n < 4; ++n)
                acc[m][n] = mfma16(a[m], b[n], acc[m][n]);
    }

    #pragma unroll
    for (int m = 0; m < 4; ++m) {
        #pragma unroll
        for (int n = 0; n < 4; ++n) {
            const int col  = bcol + wc * 64 + n * 16 + llo;
            const int row0 = brow + wr * 64 + m * 16 + lhi * 4;
            const float bv = bias[col];
            if (out_mode == 0) {
                unsigned short* O = (unsigned short*)Out;
                const int h = col >> 6, d = col & 63;
                #pragma unroll
                for (int r = 0; r < 4; ++r) {
                    int rowm = row0 + r;
                    int bb = rowm >> 11, ss = rowm & 2047;
                    O[((((size_t)bb * NHn + h) * Sn + ss) << 6) + d] =
                        f2bf((acc[m][n][r] + bv) * scale);
                }
            } else if (out_mode == 1) {
                unsigned short* O = (unsigned short*)Out;
                const int h = col >> 6, d = col & 63;
                const int bb = row0 >> 11, ss = row0 & 2047;
                union { unsigned short u[4]; bf16x4 s; } pk;
                #pragma unroll
                for (int r = 0; r < 4; ++r) pk.u[r] = f2bf(acc[m][n][r] + bv);
                *reinterpret_cast<bf16x4*>(O + (((size_t)bb * NHn + h) * HDn + d) * Sn + ss) = pk.s;
            } else {
                float* O = (float*)Out;
                #pragma unroll
                for (int r = 0; r < 4; ++r)
                    O[(size_t)(row0 + r) * Nn + col] = acc[m][n][r] + bv;
            }
        }
    }
}

__global__ __launch_bounds__(256, 2)
void qkv_proj_kernel(const float* __restrict__ xq, const float* __restrict__ xk,
                     const float* __restrict__ xv, const unsigned short* __restrict__ Wb,
                     const float* __restrict__ bq, const float* __restrict__ bk,
                     const float* __restrict__ bv,
                     unsigned short* __restrict__ Qw, unsigned short* __restrict__ Kw,
                     unsigned short* __restrict__ Vw)
{
    const int z = blockIdx.z;
    const float* A           = z == 0 ? xq : z == 1 ? xk : xv;
    const unsigned short* W  = Wb + (((size_t)z) << 20);
    const float* bias        = z == 0 ? bq : z == 1 ? bk : bv;
    unsigned short* Out      = z == 0 ? Qw : z == 1 ? Kw : Vw;
    const float scale        = z == 0 ? QSCALE : 1.0f;
    const int mode           = z == 2 ? 1 : 0;
    gemm_body<false>(A, W, bias, Out, scale, mode);
}

__global__ __launch_bounds__(256, 2)
void out_proj_kernel(const unsigned short* __restrict__ attn, const unsigned short* __restrict__ Wo,
                     const float* __restrict__ bo, float* __restrict__ out)
{
    gemm_body<true>(attn, Wo, bo, out, 1.0f, 2);
}

// ---------------- flash attention (32x32 MFMA, LDS-staged K/V, 2-phase pipeline) ----------------
// Q: [B,NH,S,64] bf16 pre-scaled by log2(e)/8.  K: [B,NH,S,64].  Vt: [B,NH,64,S].
// 4 waves/block, wave owns 32 q rows (q = lane&31; lane>>5 = half-split h).
// K/V 64-key tiles staged in LDS (XOR-swizzled, double-buffered), shared by all 4 waves.
__global__ __launch_bounds__(256, 2)
void attn_kernel(const unsigned short* __restrict__ Q, const unsigned short* __restrict__ K,
                 const unsigned short* __restrict__ Vt, unsigned short* __restrict__ On)
{
    __shared__ __align__(16) unsigned short Kl[2 * 4096];   // 2 x (64 keys x 64 d) bf16, swizzled
    __shared__ __align__(16) unsigned short Vl[2 * 4096];   // 2 x (64 d x 64 keys) bf16, swizzled

    const int tid = threadIdx.x;
    const int wid = tid >> 6, lane = tid & 63;
    const int l31 = lane & 31, h = lane >> 5;
    // XCD swizzle (T1): nwg=1024; XCD x gets heads [8x, 8x+8): K+V/head=512KB -> 4MB = one L2
    const int bid = blockIdx.x;
    const int sid = (bid & 7) * 128 + (bid >> 3);
    const int bh = sid >> 4;                 // b*16 + head
    const int qt = sid & 15;                 // 128-row q tile
    const int q0 = qt * 128 + wid * 32;

    const unsigned short* Qb = Q + (size_t)bh * Sn * HDn;
    const unsigned short* Kb = K + (size_t)bh * Sn * HDn;
    const unsigned short* Vb = Vt + (size_t)bh * HDn * Sn;

    // stage one 64-key tile (K: 8KB contiguous; V: 64 rows x 128B) with inverse-swizzled source
    auto stage = [&](int buf, int key0) {
        #pragma unroll
        for (int r = 0; r < 2; ++r) {
            int lin = (r * 256 + tid) * 16;                  // byte index in 8KB tile
            int row = lin >> 7, colb = lin & 127;
            int scolb = colb ^ ((row & 7) << 4);
            const unsigned short* g = Kb + (size_t)(key0 + row) * HDn + (scolb >> 1);
            unsigned short* ldst = Kl + buf * 4096 + r * 2048 + wid * 512;   // wave-uniform
            __builtin_amdgcn_global_load_lds((gas1_t)g, (gas3_t)ldst, 16, 0, 0);
        }
        #pragma unroll
        for (int r = 0; r < 2; ++r) {
            int lin = (r * 256 + tid) * 16;
            int row = lin >> 7, colb = lin & 127;
            int scolb = colb ^ ((row & 7) << 4);
            const unsigned short* g = Vb + (size_t)row * Sn + key0 + (scolb >> 1);
            unsigned short* ldst = Vl + buf * 4096 + r * 2048 + wid * 512;
            __builtin_amdgcn_global_load_lds((gas1_t)g, (gas3_t)ldst, 16, 0, 0);
        }
    };
    auto rdK = [&](int buf, int row, int colb) -> bf16x8 {
        return *reinterpret_cast<const bf16x8*>(
            (const char*)Kl + buf * 8192 + row * 128 + (colb ^ ((row & 7) << 4)));
    };
    auto rdV = [&](int buf, int row, int colb) -> bf16x8 {
        return *reinterpret_cast<const bf16x8*>(
            (const char*)Vl + buf * 8192 + row * 128 + (colb ^ ((row & 7) << 4)));
    };

    // Q fragment: b-operand rows = q, k = d.  4 k-steps of 16.
    bf16x8 qf[4];
    #pragma unroll
    for (int sd = 0; sd < 4; ++sd)
        qf[sd] = *reinterpret_cast<const bf16x8*>(Qb + (size_t)(q0 + l31) * HDn + sd * 16 + h * 8);

    f32x16 o0 = {}, o1 = {};
    float m_run = -1e30f, l_run = 0.f;

    stage(0, 0);
    __syncthreads();

    int cur = 0;
    constexpr int NT = Sn / 64;
    for (int kt = 0; kt < NT; ++kt) {
        if (kt + 1 < NT) stage(cur ^ 1, (kt + 1) * 64);

        // --- QK^T swapped: sc = mfma(K, Q) -> P^T[key][q], lane owns q-row l31
        f32x16 sc0 = {}, sc1 = {};
        bf16x8 ka0[4], ka1[4];
        #pragma unroll
        for (int sd = 0; sd < 4; ++sd) ka0[sd] = rdK(cur, l31,      sd * 32 + h * 16);
        #pragma unroll
        for (int sd = 0; sd < 4; ++sd) ka1[sd] = rdK(cur, 32 + l31, sd * 32 + h * 16);
        #pragma unroll
        for (int sd = 0; sd < 4; ++sd) sc0 = mfma32(ka0[sd], qf[sd], sc0);
        #pragma unroll
        for (int sd = 0; sd < 4; ++sd) sc1 = mfma32(ka1[sd], qf[sd], sc1);

        // --- V fragment reads issued early; LDS latency hides under softmax VALU
        bf16x8 va0[4], va1[4];
        #pragma unroll
        for (int S = 0; S < 4; ++S) {
            va0[S] = rdV(cur, l31,      S * 32 + h * 16);
            va1[S] = rdV(cur, 32 + l31, S * 32 + h * 16);
        }

        // --- online softmax, lane-local
        float t[16];
        #pragma unroll
        for (int r = 0; r < 16; ++r) t[r] = fmaxf(sc0[r], sc1[r]);
        #pragma unroll
        for (int st = 8; st > 0; st >>= 1)
            #pragma unroll
            for (int r = 0; r < 8; ++r)
                if (r < st) t[r] = fmaxf(t[r], t[r + st]);
        float mx = fmaxf(t[0], __shfl_xor(t[0], 32, 64));
        float mnew = fmaxf(m_run, mx);
        float corr = exp2f(m_run - mnew);
        m_run = mnew;
        #pragma unroll
        for (int r = 0; r < 16; ++r) {
            sc0[r] = exp2f(sc0[r] - mnew);
            sc1[r] = exp2f(sc1[r] - mnew);
        }
        float s[16];
        #pragma unroll
        for (int r = 0; r < 16; ++r) s[r] = sc0[r] + sc1[r];
        #pragma unroll
        for (int st = 8; st > 0; st >>= 1)
            #pragma unroll
            for (int r = 0; r < 8; ++r)
                if (r < st) s[r] += s[r + st];
        float rs = s[0] + __shfl_xor(s[0], 32, 64);
        l_run = l_run * corr + rs;
        #pragma unroll
        for (int r = 0; r < 16; ++r) { o0[r] *= corr; o1[r] *= corr; }

        // --- pack P -> bf16 words
        unsigned Wp[2][4][2];
        #pragma unroll
        for (int R = 0; R < 4; ++R) {
            Wp[0][R][0] = cvt_pk_bf16(sc0[4 * R],     sc0[4 * R + 1]);
            Wp[0][R][1] = cvt_pk_bf16(sc0[4 * R + 2], sc0[4 * R + 3]);
            Wp[1][R][0] = cvt_pk_bf16(sc1[4 * R],     sc1[4 * R + 1]);
            Wp[1][R][1] = cvt_pk_bf16(sc1[4 * R + 2], sc1[4 * R + 3]);
        }

        // --- PV: O^T += mfma(Vt, P); P b-frag assembled in-register via xor-32 swap
        #pragma unroll
        for (int kc = 0; kc < 2; ++kc) {
            #pragma unroll
            for (int sp = 0; sp < 2; ++sp) {
                const int S = kc * 2 + sp;
                unsigned own0 = h ? Wp[kc][2 * sp + 1][0] : Wp[kc][2 * sp][0];
                unsigned own1 = h ? Wp[kc][2 * sp + 1][1] : Wp[kc][2 * sp][1];
                unsigned e0   = h ? Wp[kc][2 * sp][0]     : Wp[kc][2 * sp + 1][0];
                unsigned e1   = h ? Wp[kc][2 * sp][1]     : Wp[kc][2 * sp + 1][1];
                unsigned x0 = __shfl_xor(e0, 32, 64);
                unsigned x1 = __shfl_xor(e1, 32, 64);
                union { unsigned u[4]; bf16x8 v; } pb;
                pb.u[0] = h ? x0 : own0;
                pb.u[1] = h ? x1 : own1;
                pb.u[2] = h ? own0 : x0;
                pb.u[3] = h ? own1 : x1;
                o0 = mfma32(va0[S], pb.v, o0);
                o1 = mfma32(va1[S], pb.v, o1);
            }
        }

        __syncthreads();      // drains staging vmcnt + protects cur buffer reuse
        cur ^= 1;
    }

    // --- epilogue: O^T rows d = (r&3)+8*(r>>2)+4h+32nb, col q = l31
    const float inv = 1.f / l_run;
    const int b = bh >> 4, hh = bh & 15;
    const int qg = q0 + l31;
    unsigned short* Orow = On + ((size_t)b * Sn + qg) * Hn + hh * 64;
    #pragma unroll
    for (int g = 0; g < 4; ++g) {
        union { unsigned short u[4]; bf16x4 s; } p0, p1;
        #pragma unroll
        for (int r = 0; r < 4; ++r) {
            p0.u[r] = f2bf(o0[4 * g + r] * inv);
            p1.u[r] = f2bf(o1[4 * g + r] * inv);
        }
        *reinterpret_cast<bf16x4*>(Orow + g * 8 + 4 * h)      = p0.s;
        *reinterpret_cast<bf16x4*>(Orow + 32 + g * 8 + 4 * h) = p1.s;
    }
}

// ---------------- launch ----------------
extern "C" void kernel_launch(void* const* d_in, const int* in_sizes, int n_in,
                              void* d_out, int out_size, void* d_ws, size_t ws_size,
                              hipStream_t stream)
{
    (void)in_sizes; (void)n_in; (void)out_size;
    const float* q  = (const float*)d_in[0];
    const float* k  = (const float*)d_in[1];
    const float* v  = (const float*)d_in[2];
    const float* Wq = (const float*)d_in[3];
    const float* bq = (const float*)d_in[4];
    const float* Wk = (const float*)d_in[5];
    const float* bk = (const float*)d_in[6];
    const float* Wv = (const float*)d_in[7];
    const float* bv = (const float*)d_in[8];
    const float* Wo = (const float*)d_in[9];
    const float* bo = (const float*)d_in[10];
    float* out = (float*)d_out;

    if (ws_size < (size_t)72 * 1024 * 1024) return;

    unsigned short* Wb = (unsigned short*)d_ws;
    unsigned short* Qw = Wb + (size_t)4 * 1024 * 1024;
    unsigned short* Kw = Qw + (size_t)8 * 1024 * 1024;
    unsigned short* Vw = Kw + (size_t)8 * 1024 * 1024;
    unsigned short* Aw = Vw + (size_t)8 * 1024 * 1024;

    convert_w_kernel<<<4096, 256, 0, stream>>>(Wq, Wk, Wv, Wo, Wb);
    qkv_proj_kernel<<<dim3(512, 1, 3), 256, 0, stream>>>(q, k, v, Wb, bq, bk, bv, Qw, Kw, Vw);
    attn_kernel<<<1024, 256, 0, stream>>>(Qw, Kw, Vw, Aw);
    out_proj_kernel<<<512, 256, 0, stream>>>(Aw, Wb + ((size_t)3 << 20), bo, out);
}